// Round 2
// baseline (3388.517 us; speedup 1.0000x reference)
//
#include <hip/hip_runtime.h>
#include <math.h>

#define BATCH 16
#define CDIM 256
#define NCLS 80
#define N3 16384
#define N4 4096
#define N5 1024
#define NTOK 21504
#define KQ 300
#define KSEL 512          // fp32 pre-selection width (>= KQ with huge margin)
#define CANDMAX 1024      // candidate buffer per batch (>= KSEL + tie slack)
#define MTILE 32
#define SM 36   // padded LDS row stride (32 tokens + 4 pad)

__device__ __forceinline__ float sigmoidf_(float x) {
    return 1.0f / (1.0f + __expf(-x));
}

__device__ __forceinline__ void locate_level(
    int n, int bb,
    const float* __restrict__ s3, const float* __restrict__ s4, const float* __restrict__ s5,
    const float*& src, int& nloc, int& lsz)
{
    if (n < N3)           { src = s3 + (size_t)bb * CDIM * N3; nloc = n;           lsz = N3; }
    else if (n < N3 + N4) { src = s4 + (size_t)bb * CDIM * N4; nloc = n - N3;      lsz = N4; }
    else                  { src = s5 + (size_t)bb * CDIM * N5; nloc = n - N3 - N4; lsz = N5; }
}

// -------- Kernel 1: fused encoder head (fp32) --------
// grid: BATCH * (NTOK/MTILE) blocks, 256 threads
__global__ __launch_bounds__(256, 2) void enc_kernel(
    const float* __restrict__ s3, const float* __restrict__ s4, const float* __restrict__ s5,
    const float* __restrict__ w_score, const float* __restrict__ b_score,
    const float* __restrict__ w1, const float* __restrict__ b1,
    const float* __restrict__ w2, const float* __restrict__ b2,
    const float* __restrict__ w3, const float* __restrict__ b3,
    float* __restrict__ out_logits, float* __restrict__ out_sboxes,
    float* __restrict__ ws_scores)
{
    __shared__ float memT[CDIM][SM];  // [k][token]  (reused as h2T later)
    __shared__ float hT[CDIM][SM];    // h1 transposed [k][token]

    const int t = threadIdx.x;
    const int tiles = NTOK / MTILE;               // 672
    const int bb = blockIdx.x / tiles;
    const int tile = blockIdx.x % tiles;
    const int n0 = tile * MTILE;

    const float* src; int nloc, lsz;
    locate_level(n0, bb, s3, s4, s5, src, nloc, lsz);

    // ---- Phase 0: load memory tile ([C][tok] in global already) ----
    {
        const int c0 = t >> 3;
        const int x  = t & 7;
        #pragma unroll
        for (int p = 0; p < 8; p++) {
            const int c = p * 32 + c0;
            float4 v = *(const float4*)(src + (size_t)c * lsz + nloc + 4 * x);
            *(float4*)&memT[c][4 * x] = v;
        }
    }
    __syncthreads();

    // ---- Phase 1: enc_logits (+ per-token fp32 max-sigmoid score, for pre-select only) ----
    {
        const int i = t >> 3;   // token 0..31
        const int q = t & 7;    // class group: cols 10q..10q+9
        float acc[10];
        #pragma unroll
        for (int j = 0; j < 10; j++) acc[j] = b_score[10 * q + j];
        for (int k = 0; k < CDIM; k++) {
            const float m = memT[k][i];
            const float* wr = w_score + k * NCLS + 10 * q;
            #pragma unroll
            for (int j = 0; j < 10; j++) acc[j] = fmaf(m, wr[j], acc[j]);
        }
        float* lo = out_logits + (size_t)(bb * NTOK + n0 + i) * NCLS + 10 * q;
        float mx = acc[0];
        #pragma unroll
        for (int j = 0; j < 10; j++) { lo[j] = acc[j]; mx = fmaxf(mx, acc[j]); }
        mx = fmaxf(mx, __shfl_xor(mx, 1));
        mx = fmaxf(mx, __shfl_xor(mx, 2));
        mx = fmaxf(mx, __shfl_xor(mx, 4));
        if (q == 0) ws_scores[bb * NTOK + n0 + i] = sigmoidf_(mx);
    }

    // ---- Phase 2: h1 = relu(mem @ w1 + b1) -> hT ----
    {
        const int tg = t & 7;
        const int cg = t >> 3;
        float acc[4][8];
        #pragma unroll
        for (int ii = 0; ii < 4; ii++)
            #pragma unroll
            for (int j = 0; j < 8; j++) acc[ii][j] = 0.f;
        const float* wp = w1 + 8 * cg;
        for (int k = 0; k < CDIM; k++) {
            float4 m4 = *(const float4*)&memT[k][4 * tg];
            float4 wa = *(const float4*)(wp + (size_t)k * CDIM);
            float4 wb = *(const float4*)(wp + (size_t)k * CDIM + 4);
            const float mm[4] = {m4.x, m4.y, m4.z, m4.w};
            const float wv[8] = {wa.x, wa.y, wa.z, wa.w, wb.x, wb.y, wb.z, wb.w};
            #pragma unroll
            for (int ii = 0; ii < 4; ii++)
                #pragma unroll
                for (int j = 0; j < 8; j++)
                    acc[ii][j] = fmaf(mm[ii], wv[j], acc[ii][j]);
        }
        #pragma unroll
        for (int j = 0; j < 8; j++) {
            const float bj = b1[8 * cg + j];
            float4 v;
            v.x = fmaxf(acc[0][j] + bj, 0.f);
            v.y = fmaxf(acc[1][j] + bj, 0.f);
            v.z = fmaxf(acc[2][j] + bj, 0.f);
            v.w = fmaxf(acc[3][j] + bj, 0.f);
            *(float4*)&hT[8 * cg + j][4 * tg] = v;
        }
    }
    __syncthreads();

    // ---- Phase 3: h2 = relu(h1 @ w2 + b2) -> memT ----
    {
        const int tg = t & 7;
        const int cg = t >> 3;
        float acc[4][8];
        #pragma unroll
        for (int ii = 0; ii < 4; ii++)
            #pragma unroll
            for (int j = 0; j < 8; j++) acc[ii][j] = 0.f;
        const float* wp = w2 + 8 * cg;
        for (int k = 0; k < CDIM; k++) {
            float4 m4 = *(const float4*)&hT[k][4 * tg];
            float4 wa = *(const float4*)(wp + (size_t)k * CDIM);
            float4 wb = *(const float4*)(wp + (size_t)k * CDIM + 4);
            const float mm[4] = {m4.x, m4.y, m4.z, m4.w};
            const float wv[8] = {wa.x, wa.y, wa.z, wa.w, wb.x, wb.y, wb.z, wb.w};
            #pragma unroll
            for (int ii = 0; ii < 4; ii++)
                #pragma unroll
                for (int j = 0; j < 8; j++)
                    acc[ii][j] = fmaf(mm[ii], wv[j], acc[ii][j]);
        }
        #pragma unroll
        for (int j = 0; j < 8; j++) {
            const float bj = b2[8 * cg + j];
            float4 v;
            v.x = fmaxf(acc[0][j] + bj, 0.f);
            v.y = fmaxf(acc[1][j] + bj, 0.f);
            v.z = fmaxf(acc[2][j] + bj, 0.f);
            v.w = fmaxf(acc[3][j] + bj, 0.f);
            *(float4*)&memT[8 * cg + j][4 * tg] = v;
        }
    }
    __syncthreads();

    // ---- Phase 4: enc_boxes = h2 @ w3 + b3 ; write sigmoid ----
    if (t < MTILE) {
        const int i = t;
        float acc[4] = {b3[0], b3[1], b3[2], b3[3]};
        for (int k = 0; k < CDIM; k++) {
            const float h = memT[k][i];
            #pragma unroll
            for (int c = 0; c < 4; c++) acc[c] = fmaf(h, w3[k * 4 + c], acc[c]);
        }
        float4 v;
        v.x = sigmoidf_(acc[0]); v.y = sigmoidf_(acc[1]);
        v.z = sigmoidf_(acc[2]); v.w = sigmoidf_(acc[3]);
        *(float4*)(out_sboxes + (size_t)(bb * NTOK + n0 + i) * 4) = v;
    }
}

// -------- Kernel 2: fp32 radix pre-select of top-KSEL candidates per batch --------
__global__ __launch_bounds__(256) void select_kernel(
    const float* __restrict__ scores,
    int* __restrict__ cand_idx, unsigned int* __restrict__ cand_cnt)
{
    const int bb = blockIdx.x;
    const int t = threadIdx.x;
    const float* s = scores + bb * NTOK;

    __shared__ unsigned int hist[256];
    __shared__ unsigned int prefix_s, cnt_s;

    unsigned int prefix = 0, mask = 0;
    int remaining = KSEL;
    for (int pass = 0; pass < 4; pass++) {
        const int shift = 24 - 8 * pass;
        hist[t] = 0;
        __syncthreads();
        for (int n = t; n < NTOK; n += 256) {
            unsigned int key = __float_as_uint(s[n]);   // sigmoid>0: uint order == float order
            if ((key & mask) == prefix) atomicAdd(&hist[(key >> shift) & 255u], 1u);
        }
        __syncthreads();
        if (t == 0) {
            int rem = remaining; unsigned int bsel = 0;
            for (int bin = 255; bin >= 0; bin--) {
                int c = (int)hist[bin];
                if (c >= rem) { bsel = (unsigned int)bin; break; }
                rem -= c;
            }
            prefix_s = prefix | (bsel << shift);
            hist[255] = (unsigned int)rem;   // pass remaining via LDS
        }
        __syncthreads();
        prefix = prefix_s; remaining = (int)hist[255];
        mask |= 0xFFu << shift;
        __syncthreads();
    }
    const unsigned int Tkey = prefix;   // key of the KSEL-th largest fp32 score

    if (t == 0) cnt_s = 0;
    __syncthreads();
    for (int n = t; n < NTOK; n += 256) {
        unsigned int key = __float_as_uint(s[n]);
        if (key >= Tkey) {
            unsigned int pos = atomicAdd(&cnt_s, 1u);
            if (pos < CANDMAX) cand_idx[bb * CANDMAX + pos] = n;
        }
    }
    __syncthreads();
    if (t == 0) {
        unsigned int c = cnt_s; if (c > CANDMAX) c = CANDMAX;
        cand_cnt[bb] = c;
    }
}

// -------- Kernel 3: f64 exact rescore of candidates (one wave per candidate) --------
// grid: BATCH * (CANDMAX/4) blocks, 256 threads = 4 waves
__global__ __launch_bounds__(256) void rescore_kernel(
    const float* __restrict__ s3, const float* __restrict__ s4, const float* __restrict__ s5,
    const float* __restrict__ w_score, const float* __restrict__ b_score,
    const int* __restrict__ cand_idx, const unsigned int* __restrict__ cand_cnt,
    double* __restrict__ cand_score)
{
    __shared__ float mrow[4][CDIM];
    const int t = threadIdx.x;
    const int w = t >> 6;          // wave 0..3
    const int lane = t & 63;
    const int bb = blockIdx.x / (CANDMAX / 4);
    const int c  = (blockIdx.x % (CANDMAX / 4)) * 4 + w;
    const unsigned int cnt = cand_cnt[bb];
    const bool active = (unsigned int)c < cnt;

    int n = 0;
    if (active) n = cand_idx[bb * CANDMAX + c];
    if (active) {
        const float* src; int nloc, lsz;
        locate_level(n, bb, s3, s4, s5, src, nloc, lsz);
        #pragma unroll
        for (int j = 0; j < 4; j++)
            mrow[w][4 * lane + j] = src[(size_t)(4 * lane + j) * lsz + nloc];
    }
    __syncthreads();

    if (active) {
        // lane handles class `lane`; lanes 0..15 also handle class 64+lane
        double acc0 = (double)b_score[lane];
        double acc1 = (lane < 16) ? (double)b_score[64 + lane] : -1.0e300;
        for (int k = 0; k < CDIM; k++) {
            const double m = (double)mrow[w][k];
            acc0 += m * (double)w_score[k * NCLS + lane];
            if (lane < 16) acc1 += m * (double)w_score[k * NCLS + 64 + lane];
        }
        double mx = fmax(acc0, acc1);
        mx = fmax(mx, __shfl_xor(mx, 1));
        mx = fmax(mx, __shfl_xor(mx, 2));
        mx = fmax(mx, __shfl_xor(mx, 4));
        mx = fmax(mx, __shfl_xor(mx, 8));
        mx = fmax(mx, __shfl_xor(mx, 16));
        mx = fmax(mx, __shfl_xor(mx, 32));
        if (lane == 0) cand_score[bb * CANDMAX + c] = mx;   // max-logit; sigmoid is monotone
    }
}

// -------- Kernel 4: exact sort of candidates, emit top-300 --------
__global__ __launch_bounds__(256) void fsort_kernel(
    const double* __restrict__ cand_score, const int* __restrict__ cand_idx,
    const unsigned int* __restrict__ cand_cnt,
    float* __restrict__ out_idx_f, float* __restrict__ out_scores,
    int* __restrict__ ws_idx)
{
    __shared__ double ss[CANDMAX];
    __shared__ int    ii[CANDMAX];
    const int bb = blockIdx.x;
    const int t = threadIdx.x;
    const unsigned int cnt = cand_cnt[bb];

    for (int i = t; i < CANDMAX; i += 256) {
        if ((unsigned int)i < cnt) {
            ss[i] = cand_score[bb * CANDMAX + i];
            ii[i] = cand_idx[bb * CANDMAX + i];
        } else {
            ss[i] = -1.0e300;
            ii[i] = 0x7FFFFFFF;
        }
    }
    __syncthreads();

    // bitonic sort, descending by (score desc, idx asc)
    for (int ksz = 2; ksz <= CANDMAX; ksz <<= 1) {
        for (int j = ksz >> 1; j > 0; j >>= 1) {
            #pragma unroll
            for (int p = 0; p < CANDMAX / 256; p++) {
                const int i = p * 256 + t;
                const int ixj = i ^ j;
                if (ixj > i) {
                    double sa = ss[i], sb = ss[ixj];
                    int ia = ii[i], ib = ii[ixj];
                    const bool up = ((i & ksz) != 0);
                    const bool agtb = (sa > sb) || (sa == sb && ia < ib);
                    if (agtb == up) { ss[i] = sb; ss[ixj] = sa; ii[i] = ib; ii[ixj] = ia; }
                }
            }
            __syncthreads();
        }
    }

    for (int q = t; q < KQ; q += 256) {
        const double x = ss[q];
        const int idx = ii[q];
        out_scores[bb * KQ + q] = (float)(1.0 / (1.0 + exp(-x)));
        out_idx_f[bb * KQ + q] = (float)idx;
        ws_idx[bb * KQ + q] = idx;
    }
}

// -------- Kernel 5: gather top-k memory rows, project, gather ref_points --------
__global__ __launch_bounds__(256) void gather_proj_kernel(
    const float* __restrict__ s3, const float* __restrict__ s4, const float* __restrict__ s5,
    const float* __restrict__ w_proj, const float* __restrict__ b_proj,
    const int* __restrict__ ws_idx, const float* __restrict__ out_sboxes,
    float* __restrict__ out_tgt, float* __restrict__ out_ref)
{
    __shared__ float memQ[20][CDIM];
    __shared__ int qidx[20];
    const int t = threadIdx.x;
    const int bb = blockIdx.x / 15;
    const int tile = blockIdx.x % 15;
    const int q0 = tile * 20;

    if (t < 20) qidx[t] = ws_idx[bb * KQ + q0 + t];
    __syncthreads();

    #pragma unroll 4
    for (int q = 0; q < 20; q++) {
        const int n = qidx[q];
        const float* src; int nloc, lsz;
        locate_level(n, bb, s3, s4, s5, src, nloc, lsz);
        memQ[q][t] = src[(size_t)t * lsz + nloc];
    }
    __syncthreads();

    const int j = t;
    float acc[20];
    #pragma unroll
    for (int q = 0; q < 20; q++) acc[q] = b_proj[j];
    for (int k = 0; k < CDIM; k++) {
        const float w = w_proj[(size_t)k * CDIM + j];
        #pragma unroll
        for (int q = 0; q < 20; q++) acc[q] = fmaf(memQ[q][k], w, acc[q]);
    }
    #pragma unroll
    for (int q = 0; q < 20; q++)
        out_tgt[(size_t)(bb * KQ + q0 + q) * CDIM + j] = acc[q];

    if (t < 80) {
        const int q = t >> 2, c = t & 3;
        const int n = qidx[q];
        out_ref[(size_t)(bb * KQ + q0 + q) * 4 + c] =
            out_sboxes[(size_t)(bb * NTOK + n) * 4 + c];
    }
}

extern "C" void kernel_launch(void* const* d_in, const int* in_sizes, int n_in,
                              void* d_out, int out_size, void* d_ws, size_t ws_size,
                              hipStream_t stream) {
    const float* s3      = (const float*)d_in[0];
    const float* s4      = (const float*)d_in[1];
    const float* s5      = (const float*)d_in[2];
    const float* w_score = (const float*)d_in[3];
    const float* b_score = (const float*)d_in[4];
    const float* w1      = (const float*)d_in[5];
    const float* b1      = (const float*)d_in[6];
    const float* w2      = (const float*)d_in[7];
    const float* b2      = (const float*)d_in[8];
    const float* w3      = (const float*)d_in[9];
    const float* b3      = (const float*)d_in[10];
    const float* w_proj  = (const float*)d_in[11];
    const float* b_proj  = (const float*)d_in[12];

    float* out = (float*)d_out;
    float* out_tgt    = out;                 // 16*300*256   = 1,228,800
    float* out_ref    = out + 1228800;       // 16*300*4     = 19,200
    float* out_logits = out + 1248000;       // 16*21504*80  = 27,525,120
    float* out_sboxes = out + 28773120;      // 16*21504*4   = 1,376,256
    float* out_idx    = out + 30149376;      // 16*300 (as float)
    float* out_scores = out + 30154176;      // 16*300

    // workspace layout (8B-aligned segments)
    char* ws = (char*)d_ws;
    float*        ws_scores  = (float*)ws;                                    // 16*21504*4 = 1376256
    double*       cand_score = (double*)(ws + 1376256);                       // 16*1024*8  = 131072
    int*          cand_idx   = (int*)(ws + 1376256 + 131072);                 // 16*1024*4  = 65536
    unsigned int* cand_cnt   = (unsigned int*)(ws + 1376256 + 131072 + 65536);// 16*4       = 64
    int*          ws_idx     = (int*)(ws + 1376256 + 131072 + 65536 + 64);    // 16*300*4

    enc_kernel<<<BATCH * (NTOK / MTILE), 256, 0, stream>>>(
        s3, s4, s5, w_score, b_score, w1, b1, w2, b2, w3, b3,
        out_logits, out_sboxes, ws_scores);

    select_kernel<<<BATCH, 256, 0, stream>>>(ws_scores, cand_idx, cand_cnt);

    rescore_kernel<<<BATCH * (CANDMAX / 4), 256, 0, stream>>>(
        s3, s4, s5, w_score, b_score, cand_idx, cand_cnt, cand_score);

    fsort_kernel<<<BATCH, 256, 0, stream>>>(
        cand_score, cand_idx, cand_cnt, out_idx, out_scores, ws_idx);

    gather_proj_kernel<<<BATCH * 15, 256, 0, stream>>>(
        s3, s4, s5, w_proj, b_proj, ws_idx, out_sboxes, out_tgt, out_ref);
}

// Round 3
// 948.139 us; speedup vs baseline: 3.5739x; 3.5739x over previous
//
#include <hip/hip_runtime.h>
#include <math.h>

#define BATCH 16
#define CDIM 256
#define NCLS 80
#define N3 16384
#define N4 4096
#define N5 1024
#define NTOK 21504
#define KQ 300
#define KSEL 512
#define CANDMAX 1024

typedef __attribute__((ext_vector_type(8))) short short8;
typedef __attribute__((ext_vector_type(4))) float floatx4;
typedef unsigned short ushort_t;

__device__ __forceinline__ float sigmoidf_(float x) {
    return 1.0f / (1.0f + __expf(-x));
}

__device__ __forceinline__ ushort_t f2bf(float f) {   // RNE f32->bf16
    unsigned int x = __float_as_uint(f);
    unsigned int r = (x + 0x7FFFu + ((x >> 16) & 1u)) >> 16;
    return (ushort_t)r;
}

__device__ __forceinline__ void locate_level(
    int n, int bb,
    const float* __restrict__ s3, const float* __restrict__ s4, const float* __restrict__ s5,
    const float*& src, int& nloc, int& lsz)
{
    if (n < N3)           { src = s3 + (size_t)bb * CDIM * N3; nloc = n;           lsz = N3; }
    else if (n < N3 + N4) { src = s4 + (size_t)bb * CDIM * N4; nloc = n - N3;      lsz = N4; }
    else                  { src = s5 + (size_t)bb * CDIM * N5; nloc = n - N3 - N4; lsz = N5; }
}

// -------- Kernel 0: transpose+cast weights to bf16 W^T[col][k] --------
// grid 608: c<256 -> w1T row c ; c<512 -> w2T ; c<608 -> wsT (96 rows, >=80 zero)
__global__ __launch_bounds__(256) void prep_weights(
    const float* __restrict__ w1, const float* __restrict__ w2,
    const float* __restrict__ w_score,
    ushort_t* __restrict__ w1T, ushort_t* __restrict__ w2T, ushort_t* __restrict__ wsT)
{
    const int k = threadIdx.x;
    const int c = blockIdx.x;
    if (c < 256) {
        w1T[c * 256 + k] = f2bf(w1[k * 256 + c]);
    } else if (c < 512) {
        const int c2 = c - 256;
        w2T[c2 * 256 + k] = f2bf(w2[k * 256 + c2]);
    } else {
        const int c2 = c - 512;
        wsT[c2 * 256 + k] = (c2 < NCLS) ? f2bf(w_score[k * NCLS + c2]) : (ushort_t)0;
    }
}

// -------- Kernel 1: fused encoder head, bf16 MFMA --------
// grid: BATCH * 336 blocks (64 tokens each), 256 threads = 4 waves (16 tokens/wave)
__global__ __launch_bounds__(256, 3) void enc_mfma_kernel(
    const float* __restrict__ s3, const float* __restrict__ s4, const float* __restrict__ s5,
    const ushort_t* __restrict__ w1T, const ushort_t* __restrict__ w2T,
    const ushort_t* __restrict__ wsT,
    const float* __restrict__ b_score, const float* __restrict__ b1,
    const float* __restrict__ b2,
    const float* __restrict__ w3, const float* __restrict__ b3,
    float* __restrict__ out_logits, float* __restrict__ out_sboxes,
    float* __restrict__ ws_scores)
{
    // ldsA: first memB[k=256][tok=68pad] bf16 (34816 ushorts? -> 256*68=17408 u16)
    // then reused as h1buf[tok=64][col=264pad]
    __shared__ __align__(16) ushort_t ldsA[256 * 68];     // 34816 B
    __shared__ __align__(16) ushort_t wbuf[32][264];      // 16896 B

    const int t = threadIdx.x;
    const int lane = t & 63;
    const int w = t >> 6;                 // wave id: tokens [16w,16w+16)
    const int ml = lane & 15;             // MFMA m/n lane index
    const int quad = lane >> 4;           // 0..3
    const int kq = quad * 8;              // k base within a K=32 fragment

    const int bb = blockIdx.x / 336;
    const int tile = blockIdx.x % 336;
    const int T0 = tile * 64;

    const float* src; int nloc, lsz;
    locate_level(T0, bb, s3, s4, s5, src, nloc, lsz);

    // ---- stage memory tile [k][tok] f32 -> bf16 LDS ----
    {
        const int tokq = t & 15;          // float4 group along tokens
        const int kr = t >> 4;
        #pragma unroll
        for (int p = 0; p < 16; ++p) {
            const int k = p * 16 + kr;
            const float4 v = *(const float4*)(src + (size_t)k * lsz + nloc + 4 * tokq);
            const unsigned int lo = (unsigned int)f2bf(v.x) | ((unsigned int)f2bf(v.y) << 16);
            const unsigned int hi = (unsigned int)f2bf(v.z) | ((unsigned int)f2bf(v.w) << 16);
            *(uint2*)&ldsA[k * 68 + 4 * tokq] = make_uint2(lo, hi);
        }
    }
    __syncthreads();

    // ---- A1 fragments: memory[tok=16w+ml][k] (strided u16 reads; reused GEMM1+2) ----
    short8 af[8];
    #pragma unroll
    for (int f = 0; f < 8; ++f) {
        short8 a;
        #pragma unroll
        for (int j = 0; j < 8; ++j)
            a[j] = (short)ldsA[(32 * f + kq + j) * 68 + 16 * w + ml];
        af[f] = a;
    }
    // first chunk's pre-stage barrier below also fences memB reads vs h1buf reuse

    auto stage_w = [&](const ushort_t* wg) {
        #pragma unroll
        for (int s2 = 0; s2 < 4; ++s2) {
            const int idx = s2 * 256 + t;
            const int col = idx >> 5, ks = idx & 31;
            const short8 v = *(const short8*)(wg + (size_t)col * 256 + ks * 8);
            *(short8*)&wbuf[col][ks * 8] = v;
        }
    };

    const int tokg0 = bb * NTOK + T0 + 16 * w + quad * 4;   // first global token of this lane's rows
    const int tokl0 = 16 * w + quad * 4;                    // local

    // ---- GEMM1: logits (cols 0..79; wsT padded to 96) ----
    float smax[4] = {-1e30f, -1e30f, -1e30f, -1e30f};
    for (int cc = 0; cc < 3; ++cc) {
        __syncthreads();
        stage_w(wsT + (size_t)cc * 32 * 256);
        __syncthreads();
        #pragma unroll
        for (int tt = 0; tt < 2; ++tt) {
            const int gt = cc * 2 + tt;
            if (gt >= 5) continue;                 // cols 80..95 are padding
            floatx4 acc = {0.f, 0.f, 0.f, 0.f};
            #pragma unroll
            for (int f = 0; f < 8; ++f) {
                const short8 bf = *(const short8*)&wbuf[16 * tt + ml][32 * f + kq];
                acc = __builtin_amdgcn_mfma_f32_16x16x32_bf16(af[f], bf, acc, 0, 0, 0);
            }
            const int col = 16 * gt + ml;
            const float bias = b_score[col];
            #pragma unroll
            for (int r = 0; r < 4; ++r) {
                const float v = acc[r] + bias;
                out_logits[(size_t)(tokg0 + r) * NCLS + col] = v;
                smax[r] = fmaxf(smax[r], v);
            }
        }
    }
    #pragma unroll
    for (int r = 0; r < 4; ++r) {
        float m = smax[r];
        m = fmaxf(m, __shfl_xor(m, 1));
        m = fmaxf(m, __shfl_xor(m, 2));
        m = fmaxf(m, __shfl_xor(m, 4));
        m = fmaxf(m, __shfl_xor(m, 8));
        smax[r] = m;
    }
    if (ml == 0) {
        #pragma unroll
        for (int r = 0; r < 4; ++r)
            ws_scores[bb * NTOK + T0 + 16 * w + quad * 4 + r] = sigmoidf_(smax[r]);
    }

    // ---- GEMM2: h1 = relu(mem @ w1 + b1) -> h1buf (ldsA reused: [tok][264]) ----
    for (int cc = 0; cc < 8; ++cc) {
        __syncthreads();
        stage_w(w1T + (size_t)cc * 32 * 256);
        __syncthreads();
        #pragma unroll
        for (int tt = 0; tt < 2; ++tt) {
            floatx4 acc = {0.f, 0.f, 0.f, 0.f};
            #pragma unroll
            for (int f = 0; f < 8; ++f) {
                const short8 bf = *(const short8*)&wbuf[16 * tt + ml][32 * f + kq];
                acc = __builtin_amdgcn_mfma_f32_16x16x32_bf16(af[f], bf, acc, 0, 0, 0);
            }
            const int col = 32 * cc + 16 * tt + ml;
            const float bias = b1[col];
            #pragma unroll
            for (int r = 0; r < 4; ++r) {
                const float v = fmaxf(acc[r] + bias, 0.f);
                ldsA[(tokl0 + r) * 264 + col] = f2bf(v);
            }
        }
    }
    __syncthreads();

    // ---- A2 fragments: h1[tok][k] contiguous b128 reads ----
    #pragma unroll
    for (int f = 0; f < 8; ++f)
        af[f] = *(const short8*)&ldsA[(16 * w + ml) * 264 + 32 * f + kq];

    // ---- GEMM3: h2 = relu(h1 @ w2 + b2); boxes = h2 @ w3 folded in-register ----
    float psum[4][4];
    #pragma unroll
    for (int r = 0; r < 4; ++r)
        #pragma unroll
        for (int c = 0; c < 4; ++c) psum[r][c] = 0.f;

    for (int cc = 0; cc < 8; ++cc) {
        __syncthreads();
        stage_w(w2T + (size_t)cc * 32 * 256);
        __syncthreads();
        #pragma unroll
        for (int tt = 0; tt < 2; ++tt) {
            floatx4 acc = {0.f, 0.f, 0.f, 0.f};
            #pragma unroll
            for (int f = 0; f < 8; ++f) {
                const short8 bf = *(const short8*)&wbuf[16 * tt + ml][32 * f + kq];
                acc = __builtin_amdgcn_mfma_f32_16x16x32_bf16(af[f], bf, acc, 0, 0, 0);
            }
            const int col = 32 * cc + 16 * tt + ml;
            const float bias = b2[col];
            const float4 w3v = *(const float4*)(w3 + col * 4);
            #pragma unroll
            for (int r = 0; r < 4; ++r) {
                const float v = fmaxf(acc[r] + bias, 0.f);
                psum[r][0] = fmaf(v, w3v.x, psum[r][0]);
                psum[r][1] = fmaf(v, w3v.y, psum[r][1]);
                psum[r][2] = fmaf(v, w3v.z, psum[r][2]);
                psum[r][3] = fmaf(v, w3v.w, psum[r][3]);
            }
        }
    }
    // reduce boxes partials over the 16 lanes holding different col subsets
    #pragma unroll
    for (int r = 0; r < 4; ++r)
        #pragma unroll
        for (int c = 0; c < 4; ++c) {
            float v = psum[r][c];
            v += __shfl_xor(v, 1);
            v += __shfl_xor(v, 2);
            v += __shfl_xor(v, 4);
            v += __shfl_xor(v, 8);
            psum[r][c] = v;
        }
    if (ml == 0) {
        #pragma unroll
        for (int r = 0; r < 4; ++r) {
            float4 o;
            o.x = sigmoidf_(psum[r][0] + b3[0]);
            o.y = sigmoidf_(psum[r][1] + b3[1]);
            o.z = sigmoidf_(psum[r][2] + b3[2]);
            o.w = sigmoidf_(psum[r][3] + b3[3]);
            *(float4*)&out_sboxes[(size_t)(bb * NTOK + T0 + 16 * w + quad * 4 + r) * 4] = o;
        }
    }
}

// -------- Kernel 2: fp32 radix pre-select of top-KSEL candidates per batch --------
__global__ __launch_bounds__(256) void select_kernel(
    const float* __restrict__ scores,
    int* __restrict__ cand_idx, unsigned int* __restrict__ cand_cnt)
{
    const int bb = blockIdx.x;
    const int t = threadIdx.x;
    const float* s = scores + bb * NTOK;

    __shared__ unsigned int hist[256];
    __shared__ unsigned int prefix_s, cnt_s;

    unsigned int prefix = 0, mask = 0;
    int remaining = KSEL;
    for (int pass = 0; pass < 4; pass++) {
        const int shift = 24 - 8 * pass;
        hist[t] = 0;
        __syncthreads();
        for (int n = t; n < NTOK; n += 256) {
            unsigned int key = __float_as_uint(s[n]);
            if ((key & mask) == prefix) atomicAdd(&hist[(key >> shift) & 255u], 1u);
        }
        __syncthreads();
        if (t == 0) {
            int rem = remaining; unsigned int bsel = 0;
            for (int bin = 255; bin >= 0; bin--) {
                int c = (int)hist[bin];
                if (c >= rem) { bsel = (unsigned int)bin; break; }
                rem -= c;
            }
            prefix_s = prefix | (bsel << shift);
            hist[255] = (unsigned int)rem;
        }
        __syncthreads();
        prefix = prefix_s; remaining = (int)hist[255];
        mask |= 0xFFu << shift;
        __syncthreads();
    }
    const unsigned int Tkey = prefix;

    if (t == 0) cnt_s = 0;
    __syncthreads();
    for (int n = t; n < NTOK; n += 256) {
        unsigned int key = __float_as_uint(s[n]);
        if (key >= Tkey) {
            unsigned int pos = atomicAdd(&cnt_s, 1u);
            if (pos < CANDMAX) cand_idx[bb * CANDMAX + pos] = n;
        }
    }
    __syncthreads();
    if (t == 0) {
        unsigned int c = cnt_s; if (c > CANDMAX) c = CANDMAX;
        cand_cnt[bb] = c;
    }
}

// -------- Kernel 3: f64 exact rescore (one wave per candidate) --------
__global__ __launch_bounds__(256) void rescore_kernel(
    const float* __restrict__ s3, const float* __restrict__ s4, const float* __restrict__ s5,
    const float* __restrict__ w_score, const float* __restrict__ b_score,
    const int* __restrict__ cand_idx, const unsigned int* __restrict__ cand_cnt,
    double* __restrict__ cand_score)
{
    __shared__ float mrow[4][CDIM];
    const int t = threadIdx.x;
    const int w = t >> 6;
    const int lane = t & 63;
    const int bb = blockIdx.x / (CANDMAX / 4);
    const int c  = (blockIdx.x % (CANDMAX / 4)) * 4 + w;
    const unsigned int cnt = cand_cnt[bb];
    const bool active = (unsigned int)c < cnt;

    int n = 0;
    if (active) n = cand_idx[bb * CANDMAX + c];
    if (active) {
        const float* src; int nloc, lsz;
        locate_level(n, bb, s3, s4, s5, src, nloc, lsz);
        #pragma unroll
        for (int j = 0; j < 4; j++)
            mrow[w][4 * lane + j] = src[(size_t)(4 * lane + j) * lsz + nloc];
    }
    __syncthreads();

    if (active) {
        double acc0 = (double)b_score[lane];
        double acc1 = (lane < 16) ? (double)b_score[64 + lane] : -1.0e300;
        for (int k = 0; k < CDIM; k++) {
            const double m = (double)mrow[w][k];
            acc0 += m * (double)w_score[k * NCLS + lane];
            if (lane < 16) acc1 += m * (double)w_score[k * NCLS + 64 + lane];
        }
        double mx = fmax(acc0, acc1);
        mx = fmax(mx, __shfl_xor(mx, 1));
        mx = fmax(mx, __shfl_xor(mx, 2));
        mx = fmax(mx, __shfl_xor(mx, 4));
        mx = fmax(mx, __shfl_xor(mx, 8));
        mx = fmax(mx, __shfl_xor(mx, 16));
        mx = fmax(mx, __shfl_xor(mx, 32));
        if (lane == 0) cand_score[bb * CANDMAX + c] = mx;
    }
}

// -------- Kernel 4: exact sort of candidates, emit top-300 --------
__global__ __launch_bounds__(256) void fsort_kernel(
    const double* __restrict__ cand_score, const int* __restrict__ cand_idx,
    const unsigned int* __restrict__ cand_cnt,
    float* __restrict__ out_idx_f, float* __restrict__ out_scores,
    int* __restrict__ ws_idx)
{
    __shared__ double ss[CANDMAX];
    __shared__ int    ii[CANDMAX];
    const int bb = blockIdx.x;
    const int t = threadIdx.x;
    const unsigned int cnt = cand_cnt[bb];

    for (int i = t; i < CANDMAX; i += 256) {
        if ((unsigned int)i < cnt) {
            ss[i] = cand_score[bb * CANDMAX + i];
            ii[i] = cand_idx[bb * CANDMAX + i];
        } else {
            ss[i] = -1.0e300;
            ii[i] = 0x7FFFFFFF;
        }
    }
    __syncthreads();

    for (int ksz = 2; ksz <= CANDMAX; ksz <<= 1) {
        for (int j = ksz >> 1; j > 0; j >>= 1) {
            #pragma unroll
            for (int p = 0; p < CANDMAX / 256; p++) {
                const int i = p * 256 + t;
                const int ixj = i ^ j;
                if (ixj > i) {
                    double sa = ss[i], sb = ss[ixj];
                    int ia = ii[i], ib = ii[ixj];
                    const bool up = ((i & ksz) != 0);
                    const bool agtb = (sa > sb) || (sa == sb && ia < ib);
                    if (agtb == up) { ss[i] = sb; ss[ixj] = sa; ii[i] = ib; ii[ixj] = ia; }
                }
            }
            __syncthreads();
        }
    }

    for (int q = t; q < KQ; q += 256) {
        const double x = ss[q];
        const int idx = ii[q];
        out_scores[bb * KQ + q] = (float)(1.0 / (1.0 + exp(-x)));
        out_idx_f[bb * KQ + q] = (float)idx;
        ws_idx[bb * KQ + q] = idx;
    }
}

// -------- Kernel 5: gather top-k memory rows, project, gather ref_points --------
__global__ __launch_bounds__(256) void gather_proj_kernel(
    const float* __restrict__ s3, const float* __restrict__ s4, const float* __restrict__ s5,
    const float* __restrict__ w_proj, const float* __restrict__ b_proj,
    const int* __restrict__ ws_idx, const float* __restrict__ out_sboxes,
    float* __restrict__ out_tgt, float* __restrict__ out_ref)
{
    __shared__ float memQ[20][CDIM];
    __shared__ int qidx[20];
    const int t = threadIdx.x;
    const int bb = blockIdx.x / 15;
    const int tile = blockIdx.x % 15;
    const int q0 = tile * 20;

    if (t < 20) qidx[t] = ws_idx[bb * KQ + q0 + t];
    __syncthreads();

    #pragma unroll 4
    for (int q = 0; q < 20; q++) {
        const int n = qidx[q];
        const float* src; int nloc, lsz;
        locate_level(n, bb, s3, s4, s5, src, nloc, lsz);
        memQ[q][t] = src[(size_t)t * lsz + nloc];
    }
    __syncthreads();

    const int j = t;
    float acc[20];
    #pragma unroll
    for (int q = 0; q < 20; q++) acc[q] = b_proj[j];
    for (int k = 0; k < CDIM; k++) {
        const float w = w_proj[(size_t)k * CDIM + j];
        #pragma unroll
        for (int q = 0; q < 20; q++) acc[q] = fmaf(memQ[q][k], w, acc[q]);
    }
    #pragma unroll
    for (int q = 0; q < 20; q++)
        out_tgt[(size_t)(bb * KQ + q0 + q) * CDIM + j] = acc[q];

    if (t < 80) {
        const int q = t >> 2, c = t & 3;
        const int n = qidx[q];
        out_ref[(size_t)(bb * KQ + q0 + q) * 4 + c] =
            out_sboxes[(size_t)(bb * NTOK + n) * 4 + c];
    }
}

extern "C" void kernel_launch(void* const* d_in, const int* in_sizes, int n_in,
                              void* d_out, int out_size, void* d_ws, size_t ws_size,
                              hipStream_t stream) {
    const float* s3      = (const float*)d_in[0];
    const float* s4      = (const float*)d_in[1];
    const float* s5      = (const float*)d_in[2];
    const float* w_score = (const float*)d_in[3];
    const float* b_score = (const float*)d_in[4];
    const float* w1      = (const float*)d_in[5];
    const float* b1      = (const float*)d_in[6];
    const float* w2      = (const float*)d_in[7];
    const float* b2      = (const float*)d_in[8];
    const float* w3      = (const float*)d_in[9];
    const float* b3      = (const float*)d_in[10];
    const float* w_proj  = (const float*)d_in[11];
    const float* b_proj  = (const float*)d_in[12];

    float* out = (float*)d_out;
    float* out_tgt    = out;                 // 16*300*256
    float* out_ref    = out + 1228800;       // 16*300*4
    float* out_logits = out + 1248000;       // 16*21504*80
    float* out_sboxes = out + 28773120;      // 16*21504*4
    float* out_idx    = out + 30149376;      // 16*300 (as float)
    float* out_scores = out + 30154176;      // 16*300

    char* ws = (char*)d_ws;
    float*        ws_scores  = (float*)(ws + 0);            // 1,376,256
    double*       cand_score = (double*)(ws + 1376256);     //   131,072
    int*          cand_idx   = (int*)(ws + 1507328);        //    65,536
    unsigned int* cand_cnt   = (unsigned int*)(ws + 1572864); //      256
    int*          ws_idx     = (int*)(ws + 1573120);        //    19,456
    ushort_t*     w1T        = (ushort_t*)(ws + 1592576);   //   131,072
    ushort_t*     w2T        = (ushort_t*)(ws + 1723648);   //   131,072
    ushort_t*     wsT        = (ushort_t*)(ws + 1854720);   //    49,152

    prep_weights<<<608, 256, 0, stream>>>(w1, w2, w_score, w1T, w2T, wsT);

    enc_mfma_kernel<<<BATCH * 336, 256, 0, stream>>>(
        s3, s4, s5, w1T, w2T, wsT, b_score, b1, b2, w3, b3,
        out_logits, out_sboxes, ws_scores);

    select_kernel<<<BATCH, 256, 0, stream>>>(ws_scores, cand_idx, cand_cnt);

    rescore_kernel<<<BATCH * (CANDMAX / 4), 256, 0, stream>>>(
        s3, s4, s5, w_score, b_score, cand_idx, cand_cnt, cand_score);

    fsort_kernel<<<BATCH, 256, 0, stream>>>(
        cand_score, cand_idx, cand_cnt, out_idx, out_scores, ws_idx);

    gather_proj_kernel<<<BATCH * 15, 256, 0, stream>>>(
        s3, s4, s5, w_proj, b_proj, ws_idx, out_sboxes, out_tgt, out_ref);
}